// Round 7
// baseline (595.448 us; speedup 1.0000x reference)
//
#include <hip/hip_runtime.h>
#include <cstdint>

#define NHEAD 8
#define D1 64      // H1*C1
#define IN_F 128
#define NEG 0.2f
#define NBINS 256  // loss partial-sum bins
#define BINS 1024  // dst buckets of 128 nodes each (bin = dst>>7); valid for N <= 131072
#define BSH 7
#define CHUNK 8192 // edges per hist/scatter block (32/thread)

__device__ __forceinline__ void fma4(float4& a, float s, const float4& v)
{
    a.x = fmaf(s, v.x, a.x); a.y = fmaf(s, v.y, a.y);
    a.z = fmaf(s, v.z, a.z); a.w = fmaf(s, v.w, a.w);
}

// ---------------- Fused: bucket-hist (first) & gemm1 ---------------------------
__global__ __launch_bounds__(256) void k_gemm1_hist(
    const float* __restrict__ feat,
    const float* __restrict__ W1,
    const float* __restrict__ att_s,
    const float* __restrict__ att_d,
    float* __restrict__ h1, float* __restrict__ a_src, float* __restrict__ a_dst,
    const int* __restrict__ dst, int* __restrict__ btot, int* __restrict__ bh,
    int N, int E, int GH)
{
    __shared__ float Wh[32 * 64];   // gemm: [kk][c], 8 KB (hist reuses as int hist[1024])
    __shared__ float Fh[64 * 36];   // gemm: [r][kk], stride 36, 9.2 KB
    const int tid = threadIdx.x;

    if ((int)blockIdx.x < GH) {
        // -------- histogram branch: all per-edge atomics in LDS ---------------
        int* hist = (int*)Wh;
        for (int b = tid; b < BINS; b += 256) hist[b] = 0;
        __syncthreads();
        const int e0 = blockIdx.x * CHUNK;
        #pragma unroll
        for (int r = 0; r < 8; ++r) {
            int e = e0 + r * 1024 + tid * 4;
            if (e + 3 < E) {
                int4 d4 = *(const int4*)&dst[e];
                atomicAdd(&hist[d4.x >> BSH], 1);
                atomicAdd(&hist[d4.y >> BSH], 1);
                atomicAdd(&hist[d4.z >> BSH], 1);
                atomicAdd(&hist[d4.w >> BSH], 1);
            } else {
                for (int k = e; k < E && k < e + 4; ++k)
                    atomicAdd(&hist[dst[k] >> BSH], 1);
            }
        }
        __syncthreads();
        for (int b = tid; b < BINS; b += 256) {
            int c = hist[b];
            bh[(size_t)blockIdx.x * BINS + b] = c;      // coalesced 4 KB store
            if (c) atomicAdd(&btot[b * 16], c);         // no-return, padded line
        }
        return;
    }

    // -------- gemm1 branch: 64x64 tile, 4x4 register tile, K in 4 quarters ----
    const int tx = tid & 15, ty = tid >> 4;
    const int base = (blockIdx.x - GH) * 64;
    float4 acc0 = {0,0,0,0}, acc1 = {0,0,0,0}, acc2 = {0,0,0,0}, acc3 = {0,0,0,0};

    for (int p = 0; p < 4; ++p) {
        if (p) __syncthreads();
        for (int i = tid; i < 32 * 64; i += 256)
            Wh[i] = W1[p * 2048 + i];
        for (int i = tid; i < 64 * 32; i += 256) {
            int r = i >> 5, kk = i & 31;
            int n = base + r;
            Fh[r * 36 + kk] = (n < N) ? feat[(size_t)n * IN_F + p * 32 + kk] : 0.f;
        }
        __syncthreads();
        const float* wk = &Wh[4 * tx];
        const float* f0 = &Fh[(4 * ty + 0) * 36];
        const float* f1 = &Fh[(4 * ty + 1) * 36];
        const float* f2 = &Fh[(4 * ty + 2) * 36];
        const float* f3 = &Fh[(4 * ty + 3) * 36];
        #pragma unroll
        for (int kk = 0; kk < 32; kk += 4) {
            float4 fa = *(const float4*)&f0[kk];
            float4 fb = *(const float4*)&f1[kk];
            float4 fc = *(const float4*)&f2[kk];
            float4 fd = *(const float4*)&f3[kk];
            float4 w0 = *(const float4*)&wk[(kk + 0) * 64];
            float4 w1 = *(const float4*)&wk[(kk + 1) * 64];
            float4 w2 = *(const float4*)&wk[(kk + 2) * 64];
            float4 w3 = *(const float4*)&wk[(kk + 3) * 64];
            fma4(acc0, fa.x, w0); fma4(acc0, fa.y, w1); fma4(acc0, fa.z, w2); fma4(acc0, fa.w, w3);
            fma4(acc1, fb.x, w0); fma4(acc1, fb.y, w1); fma4(acc1, fb.z, w2); fma4(acc1, fb.w, w3);
            fma4(acc2, fc.x, w0); fma4(acc2, fc.y, w1); fma4(acc2, fc.z, w2); fma4(acc2, fc.w, w3);
            fma4(acc3, fd.x, w0); fma4(acc3, fd.y, w1); fma4(acc3, fd.z, w2); fma4(acc3, fd.w, w3);
        }
    }
    const float4 as4 = *(const float4*)&att_s[4 * tx];
    const float4 ad4 = *(const float4*)&att_d[4 * tx];
    float4 accs[4] = {acc0, acc1, acc2, acc3};
    #pragma unroll
    for (int i = 0; i < 4; ++i) {
        int n = base + 4 * ty + i;
        if (n < N) {
            *(float4*)&h1[(size_t)n * D1 + 4 * tx] = accs[i];
            float ps = accs[i].x * as4.x + accs[i].y * as4.y + accs[i].z * as4.z + accs[i].w * as4.w;
            float pd = accs[i].x * ad4.x + accs[i].y * ad4.y + accs[i].z * ad4.z + accs[i].w * ad4.w;
            ps += __shfl_xor(ps, 1);
            pd += __shfl_xor(pd, 1);
            if ((tx & 1) == 0) {
                a_src[n * NHEAD + (tx >> 1)] = ps;
                a_dst[n * NHEAD + (tx >> 1)] = pd;
            }
        }
    }
}

__device__ __forceinline__ int block_incl_scan(int v, int tid, int* lds4)
{
    int lane = tid & 63, w = tid >> 6;
    #pragma unroll
    for (int off = 1; off < 64; off <<= 1) {
        int t = __shfl_up(v, off);
        if (lane >= off) v += t;
    }
    if (lane == 63) lds4[w] = v;
    __syncthreads();
    int add = 0;
    #pragma unroll
    for (int i = 0; i < 4; ++i)
        if (i < w) add += lds4[i];
    __syncthreads();
    return v + add;
}

// Scan bucket totals -> bases; init cursors; zero loss bins and last-block ticket.
__global__ __launch_bounds__(256) void k_bscan(
    const int* __restrict__ btot, int* __restrict__ bbase, int* __restrict__ gcur,
    double* __restrict__ bins, int* __restrict__ lcnt)
{
    __shared__ int lds4[4];
    const int tid = threadIdx.x;
    bins[tid] = 0.0;
    if (tid == 0) lcnt[0] = 0;
    int c0 = btot[(4 * tid + 0) * 16];
    int c1 = btot[(4 * tid + 1) * 16];
    int c2 = btot[(4 * tid + 2) * 16];
    int c3 = btot[(4 * tid + 3) * 16];
    int v = c0 + c1 + c2 + c3;
    int incl = block_incl_scan(v, tid, lds4);
    int b0 = incl - v, b1 = b0 + c0, b2 = b1 + c1, b3 = b2 + c2;
    bbase[4 * tid + 0] = b0; gcur[(4 * tid + 0) * 16] = b0;
    bbase[4 * tid + 1] = b1; gcur[(4 * tid + 1) * 16] = b1;
    bbase[4 * tid + 2] = b2; gcur[(4 * tid + 2) * 16] = b2;
    bbase[4 * tid + 3] = b3; gcur[(4 * tid + 3) * 16] = b3;
}

// Scatter edges into their dst-bucket. Packed entry: (dst&127)<<17 | src.
__global__ __launch_bounds__(256) void k_scatter(
    const int* __restrict__ src, const int* __restrict__ dst,
    const int* __restrict__ bh, int* __restrict__ gcur,
    int* __restrict__ bucketed, int E)
{
    __shared__ int base[BINS], cur[BINS];
    const int tid = threadIdx.x;
    for (int b = tid; b < BINS; b += 256) {
        cur[b] = 0;
        int c = bh[(size_t)blockIdx.x * BINS + b];
        if (c) base[b] = atomicAdd(&gcur[b * 16], c);
    }
    __syncthreads();
    const int e0 = blockIdx.x * CHUNK;
    #pragma unroll
    for (int r = 0; r < 8; ++r) {
        int e = e0 + r * 1024 + tid * 4;
        if (e + 3 < E) {
            int4 d4 = *(const int4*)&dst[e];
            int4 s4 = *(const int4*)&src[e];
            int bx, rx;
            bx = d4.x >> BSH; rx = atomicAdd(&cur[bx], 1); bucketed[base[bx] + rx] = ((d4.x & 127) << 17) | s4.x;
            bx = d4.y >> BSH; rx = atomicAdd(&cur[bx], 1); bucketed[base[bx] + rx] = ((d4.y & 127) << 17) | s4.y;
            bx = d4.z >> BSH; rx = atomicAdd(&cur[bx], 1); bucketed[base[bx] + rx] = ((d4.z & 127) << 17) | s4.z;
            bx = d4.w >> BSH; rx = atomicAdd(&cur[bx], 1); bucketed[base[bx] + rx] = ((d4.w & 127) << 17) | s4.w;
        } else {
            for (int k = e; k < E && k < e + 4; ++k) {
                int d = dst[k];
                int bx = d >> BSH;
                int rx = atomicAdd(&cur[bx], 1);
                bucketed[base[bx] + rx] = ((d & 127) << 17) | src[k];
            }
        }
    }
}

// One block per bucket -> deg/rowstart/srcs.
__global__ __launch_bounds__(256) void k_seg(
    const int* __restrict__ btot, const int* __restrict__ bbase,
    const int* __restrict__ bucketed,
    int* __restrict__ deg, int* __restrict__ rowstart, int* __restrict__ srcs, int N)
{
    __shared__ int cnt[128], cur[128], lb[128];
    const int tid = threadIdx.x;
    const int b = blockIdx.x;
    const int gs = bbase[b];
    const int sz = btot[b * 16];
    if (tid < 128) { cnt[tid] = 0; cur[tid] = 0; }
    __syncthreads();
    for (int i = tid; i < sz; i += 256)
        atomicAdd(&cnt[bucketed[gs + i] >> 17], 1);
    __syncthreads();
    if (tid < 128) lb[tid] = cnt[tid];
    __syncthreads();
    #pragma unroll
    for (int off = 1; off < 128; off <<= 1) {
        int t = 0;
        if (tid < 128 && tid >= off) t = lb[tid - off];
        __syncthreads();
        if (tid < 128 && tid >= off) lb[tid] += t;
        __syncthreads();
    }
    if (tid < 128) {
        int ex = lb[tid] - cnt[tid];   // exclusive local base
        lb[tid] = ex;
        int d = b * 128 + tid;
        if (d < N) { deg[d] = cnt[tid]; rowstart[d] = gs + ex; }
    }
    __syncthreads();
    for (int i = tid; i < sz; i += 256) {
        int v = bucketed[gs + i];
        int d7 = v >> 17;
        int r = atomicAdd(&cur[d7], 1);
        srcs[gs + lb[d7] + r] = v & 0x1FFFF;
    }
}

// ---------------- Layer-1 aggregation FUSED with gemm2 -------------------------
// Round-19: k_gemm2's only input was agg1's x. Fuse: after the gather/merge, the
// wave holds the x row in 16 lanes; stage it in wave-private LDS, compute
// h2[j] = sum_k x[k]*W2[k][j] as the SAME sequential k=0..63 fmaf chain gemm2
// used (bit-identical h2), land h2 in gemm2's 16-lane float4 layout and reuse
// its ps/pd code verbatim (bit-identical a_s2/a_d2). Deletes the gemm2 kernel,
// the x write (25.6 MB) and re-read. W2 staged once per block; grid-stride over
// nodes at 2048 blocks keeps W2 traffic nil (16 KB, L2-resident) and
// occupancy unchanged (18.3 KB LDS -> 8 blocks/CU).
__global__ __launch_bounds__(256) void k_agg1f(
    const int* __restrict__ deg, const int* __restrict__ rowstart,
    const int* __restrict__ srcs,
    const float* __restrict__ a_s, const float* __restrict__ a_d,
    const float* __restrict__ h1, const float* __restrict__ b1,
    const float* __restrict__ W2,
    const float* __restrict__ att_s2, const float* __restrict__ att_d2,
    float* __restrict__ h2, float* __restrict__ a_s2, float* __restrict__ a_d2,
    int N)
{
    __shared__ float W2s[64 * 64];   // [k][c], 16 KB
    __shared__ float xrow[4][64];    // wave-private x staging
    __shared__ float h2row[4][64];   // wave-private h2 staging
    const int tid = threadIdx.x, w = tid >> 6, j = tid & 63;
    const int t = j & 15, q = j >> 4;
    const int h = t >> 1;
    for (int i = tid; i < 64 * 64; i += 256) W2s[i] = W2[i];
    __syncthreads();
    const float4 bb  = *(const float4*)&b1[4 * t];
    const float4 as4 = *(const float4*)&att_s2[4 * t];
    const float4 ad4 = *(const float4*)&att_d2[4 * t];

    for (int n = blockIdx.x * 4 + w; n < N; n += gridDim.x * 4) {
        const int rlen = deg[n];
        const int row = rowstart[n];
        const float ad = a_d[n * NHEAD + h];
        float4 acc = {0.f, 0.f, 0.f, 0.f};
        float den = 0.f;
        for (int base = 0; base < rlen; base += 16) {
            int mTot = rlen - base;
            if (4 * q < mTot) {
                int rem = mTot - 4 * q;
                int i0 = row + base + 4 * q;
                int s0 = srcs[i0];
                int s1 = rem > 1 ? srcs[i0 + 1] : 0;
                int s2 = rem > 2 ? srcs[i0 + 2] : 0;
                int s3 = rem > 3 ? srcs[i0 + 3] : 0;
                float v0 = a_s[s0 * NHEAD + h] + ad;
                float v1 = a_s[s1 * NHEAD + h] + ad;
                float v2 = a_s[s2 * NHEAD + h] + ad;
                float v3 = a_s[s3 * NHEAD + h] + ad;
                v0 = v0 > 0.f ? v0 : NEG * v0;
                v1 = v1 > 0.f ? v1 : NEG * v1;
                v2 = v2 > 0.f ? v2 : NEG * v2;
                v3 = v3 > 0.f ? v3 : NEG * v3;
                float e0 = __expf(v0);
                float e1 = rem > 1 ? __expf(v1) : 0.f;
                float e2 = rem > 2 ? __expf(v2) : 0.f;
                float e3 = rem > 3 ? __expf(v3) : 0.f;
                float4 l0 = *(const float4*)&h1[(size_t)s0 * D1 + 4 * t];
                float4 l1 = *(const float4*)&h1[(size_t)s1 * D1 + 4 * t];
                float4 l2 = *(const float4*)&h1[(size_t)s2 * D1 + 4 * t];
                float4 l3 = *(const float4*)&h1[(size_t)s3 * D1 + 4 * t];
                fma4(acc, e0, l0); fma4(acc, e1, l1);
                fma4(acc, e2, l2); fma4(acc, e3, l3);
                den += (e0 + e1) + (e2 + e3);
            }
        }
        // merge the 4 q-replicas (den rides along)
        acc.x += __shfl_xor(acc.x, 16); acc.y += __shfl_xor(acc.y, 16);
        acc.z += __shfl_xor(acc.z, 16); acc.w += __shfl_xor(acc.w, 16);
        den   += __shfl_xor(den, 16);
        acc.x += __shfl_xor(acc.x, 32); acc.y += __shfl_xor(acc.y, 32);
        acc.z += __shfl_xor(acc.z, 32); acc.w += __shfl_xor(acc.w, 32);
        den   += __shfl_xor(den, 32);
        if (q == 0) {
            float4 o;
            o.x = acc.x / den + bb.x; o.y = acc.y / den + bb.y;
            o.z = acc.z / den + bb.z; o.w = acc.w / den + bb.w;
            o.x = o.x > 0.f ? o.x : expm1f(o.x);
            o.y = o.y > 0.f ? o.y : expm1f(o.y);
            o.z = o.z > 0.f ? o.z : expm1f(o.z);
            o.w = o.w > 0.f ? o.w : expm1f(o.w);
            *(float4*)&xrow[w][4 * t] = o;
        }
        asm volatile("s_waitcnt lgkmcnt(0)" ::: "memory");
        // h2[j] = sum_{k=0..63} x[k]*W2[k][j] -- sequential chain == old gemm2
        float hj = 0.f;
        #pragma unroll 16
        for (int k = 0; k < 64; ++k)
            hj = fmaf(xrow[w][k], W2s[k * 64 + j], hj);
        h2row[w][j] = hj;
        asm volatile("s_waitcnt lgkmcnt(0)" ::: "memory");
        if (q == 0) {
            float4 hv = *(const float4*)&h2row[w][4 * t];
            *(float4*)&h2[(size_t)n * 64 + 4 * t] = hv;
            float ps = hv.x * as4.x + hv.y * as4.y + hv.z * as4.z + hv.w * as4.w;
            float pd = hv.x * ad4.x + hv.y * ad4.y + hv.z * ad4.z + hv.w * ad4.w;
            ps += __shfl_xor(ps, 1); pd += __shfl_xor(pd, 1);
            ps += __shfl_xor(ps, 2); pd += __shfl_xor(pd, 2);
            ps += __shfl_xor(ps, 4); pd += __shfl_xor(pd, 4);
            ps += __shfl_xor(ps, 8); pd += __shfl_xor(pd, 8);
            if (t == 0) { a_s2[n] = ps; a_d2[n] = pd; }
        }
    }
}

// ---------------- Layer-2 aggregation + softmax + NLL + fused loss reduce ------
__global__ __launch_bounds__(256) void k_agg2(
    const int* __restrict__ deg, const int* __restrict__ rowstart,
    const int* __restrict__ srcs,
    const float* __restrict__ a_s, const float* __restrict__ a_d,
    const float* __restrict__ h2, const float* __restrict__ b2,
    const int* __restrict__ label,
    float* __restrict__ dout, double* __restrict__ bins, int* __restrict__ lcnt,
    int N)
{
    __shared__ float snll[16];
    __shared__ int lastFlag;
    __shared__ double sw[4];
    const int tid = threadIdx.x, j = tid & 63;
    const int t = j & 15, g16 = j & 0x30;  // node's 16-lane group base within wave
    const int n = blockIdx.x * 16 + (tid >> 4);
    if (tid < 16) snll[tid] = 0.f;
    __syncthreads();
    const bool valid = (n < N);
    const int rlen = valid ? deg[n] : 0;
    const int row  = valid ? rowstart[n] : 0;
    const float ad = valid ? a_d[n] : 0.f;
    float4 acc = {0.f, 0.f, 0.f, 0.f};
    float den = 0.f;
    for (int base = 0; base < rlen; base += 16) {
        int m = rlen - base; if (m > 16) m = 16;
        int myS = 0; float ex = 0.f;
        if (t < m) {
            myS = srcs[row + base + t];
            float v = a_s[myS] + ad;
            v = v > 0.f ? v : NEG * v;
            ex = __expf(v);
        }
        float ds = ex;
        ds += __shfl_xor(ds, 1); ds += __shfl_xor(ds, 2);
        ds += __shfl_xor(ds, 4); ds += __shfl_xor(ds, 8);
        den += ds;
        for (int kb = 0; kb < m; kb += 4) {            // kb in {0,4,8,12}
            int s0 = __shfl(myS, g16 | (kb + 0));
            int s1 = __shfl(myS, g16 | (kb + 1));
            int s2 = __shfl(myS, g16 | (kb + 2));
            int s3 = __shfl(myS, g16 | (kb + 3));
            float e0 = __shfl(ex, g16 | (kb + 0));
            float e1 = __shfl(ex, g16 | (kb + 1));
            float e2 = __shfl(ex, g16 | (kb + 2));
            float e3 = __shfl(ex, g16 | (kb + 3));
            float4 l0 = *(const float4*)&h2[(size_t)s0 * 64 + 4 * t];
            float4 l1 = *(const float4*)&h2[(size_t)s1 * 64 + 4 * t];
            float4 l2 = *(const float4*)&h2[(size_t)s2 * 64 + 4 * t];
            float4 l3 = *(const float4*)&h2[(size_t)s3 * 64 + 4 * t];
            fma4(acc, e0, l0);
            fma4(acc, e1, l1);
            fma4(acc, e2, l2);
            fma4(acc, e3, l3);
        }
    }
    float4 b = *(const float4*)&b2[4 * t];
    float4 sc;
    sc.x = acc.x / den + b.x; sc.y = acc.y / den + b.y;
    sc.z = acc.z / den + b.z; sc.w = acc.w / den + b.w;
    float mv = sc.x; int mi = 4 * t;
    if (sc.y > mv) { mv = sc.y; mi = 4 * t + 1; }
    if (sc.z > mv) { mv = sc.z; mi = 4 * t + 2; }
    if (sc.w > mv) { mv = sc.w; mi = 4 * t + 3; }
    #pragma unroll
    for (int off = 1; off < 16; off <<= 1) {
        float ov = __shfl_xor(mv, off);
        int oi = __shfl_xor(mi, off);
        if (ov > mv || (ov == mv && oi < mi)) { mv = ov; mi = oi; }
    }
    float se = __expf(sc.x - mv) + __expf(sc.y - mv) + __expf(sc.z - mv) + __expf(sc.w - mv);
    #pragma unroll
    for (int off = 1; off < 16; off <<= 1) se += __shfl_xor(se, off);
    int lab = valid ? label[n] : 0;
    int comp = lab & 3;
    float cl = comp == 0 ? sc.x : comp == 1 ? sc.y : comp == 2 ? sc.z : sc.w;
    float sl = __shfl(cl, g16 | (lab >> 2));
    if (t == 0 && valid) {
        snll[tid >> 4] = mv + logf(se) - sl;
        dout[1 + n] = (float)mi;
        dout[1 + (size_t)N + n] = (float)lab;
    }
    __syncthreads();
    if (tid == 0) {
        double bs = 0.0;
        #pragma unroll
        for (int i = 0; i < 16; ++i) bs += (double)snll[i];
        atomicAdd(&bins[blockIdx.x & (NBINS - 1)], bs);
        __threadfence();
        lastFlag = (atomicAdd(lcnt, 1) == (int)gridDim.x - 1);
    }
    __syncthreads();
    if (lastFlag) {
        // last block: all prior bins atomics visible (ticket ordered after fence)
        double v = atomicAdd(&bins[tid], 0.0);   // coherent read
        #pragma unroll
        for (int off = 1; off < 64; off <<= 1) v += __shfl_xor(v, off);
        if ((tid & 63) == 0) sw[tid >> 6] = v;
        __syncthreads();
        if (tid == 0)
            dout[0] = (float)((sw[0] + sw[1] + sw[2] + sw[3]) / (double)N);
    }
}

extern "C" void kernel_launch(void* const* d_in, const int* in_sizes, int n_in,
                              void* d_out, int out_size, void* d_ws, size_t ws_size,
                              hipStream_t stream)
{
    const float* feat   = (const float*)d_in[1];
    const int*   edge   = (const int*)d_in[2];
    const int*   label  = (const int*)d_in[4];
    const float* W1     = (const float*)d_in[5];
    const float* att_s1 = (const float*)d_in[6];
    const float* att_d1 = (const float*)d_in[7];
    const float* b1     = (const float*)d_in[8];
    const float* W2     = (const float*)d_in[9];
    const float* att_s2 = (const float*)d_in[10];
    const float* att_d2 = (const float*)d_in[11];
    const float* b2     = (const float*)d_in[12];

    const int N = in_sizes[0];
    const int E = in_sizes[2] / 2;
    const int* src = edge;
    const int* dst = edge + E;

    // workspace layout:
    float* bufA = (float*)d_ws;               // N*64: h1
    float* bufB = bufA + (size_t)N * 64;      // N*64: h2; aliases CSR-build scratch
    float* a_s1 = bufB + (size_t)N * 64;      // N*8
    float* a_d1 = a_s1 + (size_t)N * 8;       // N*8
    int*   deg  = (int*)(a_d1 + (size_t)N * 8); // N
    int*   rowstart = deg + N;                // N (absolute CSR row starts)
    int*   srcs = rowstart + N;               // E
    double* bins = (double*)(((uintptr_t)(srcs + E) + 7) & ~(uintptr_t)7);
    int*   lcnt = (int*)(bins + NBINS);       // last-block ticket
    float* a_s2 = (float*)(lcnt + 4);         // N  (NOT aliased with a_s1: agg1f
    float* a_d2 = a_s2 + N;                   // N   writes these while reading a_s1)

    // Aliases in bufB — all dead before k_agg1f writes h2:
    int* bucketed = (int*)bufB;               // E   packed (dst&127)<<17 | src
    int* btot  = bucketed + E;                // BINS*16 (padded: 1 counter / 64B line)
    int* gcur  = btot + BINS * 16;            // BINS*16 (padded cursors)
    int* bbase = gcur + BINS * 16;            // BINS
    int* bh    = bbase + BINS;                // GH*BINS per-block histograms

    float* out = (float*)d_out;

    const int GH    = (E + CHUNK - 1) / CHUNK;
    const int G1    = (N + 63) / 64;
    const int NBUCK = (N + 127) / 128;

    hipMemsetAsync(btot, 0, (size_t)BINS * 16 * sizeof(int), stream);

    k_gemm1_hist<<<GH + G1, 256, 0, stream>>>(feat, W1, att_s1, att_d1,
                                              bufA, a_s1, a_d1,
                                              dst, btot, bh, N, E, GH);
    k_bscan  <<<1, 256, 0, stream>>>(btot, bbase, gcur, bins, lcnt);
    k_scatter<<<GH, 256, 0, stream>>>(src, dst, bh, gcur, bucketed, E);
    k_seg    <<<NBUCK, 256, 0, stream>>>(btot, bbase, bucketed, deg, rowstart, srcs, N);

    k_agg1f<<<2048, 256, 0, stream>>>(deg, rowstart, srcs, a_s1, a_d1,
                                      bufA, b1, W2, att_s2, att_d2,
                                      bufB, a_s2, a_d2, N);
    k_agg2 <<<(N + 15) / 16, 256, 0, stream>>>(deg, rowstart, srcs, a_s2, a_d2,
                                               bufB, b2, label, out, bins, lcnt, N);
}

// Round 8
// 385.513 us; speedup vs baseline: 1.5446x; 1.5446x over previous
//
#include <hip/hip_runtime.h>
#include <cstdint>

#define NHEAD 8
#define D1 64      // H1*C1
#define IN_F 128
#define NEG 0.2f
#define NBINS 256  // loss partial-sum bins
#define BINS 1024  // dst buckets of 128 nodes each (bin = dst>>7); valid for N <= 131072
#define BSH 7
#define CHUNK 8192 // edges per hist/scatter block (32/thread)

__device__ __forceinline__ void fma4(float4& a, float s, const float4& v)
{
    a.x = fmaf(s, v.x, a.x); a.y = fmaf(s, v.y, a.y);
    a.z = fmaf(s, v.z, a.z); a.w = fmaf(s, v.w, a.w);
}

// ---------------- Fused: bucket-hist (first) & gemm1 ---------------------------
// R8: full revert to the R6 structure (measured 393.6 us).
// R7 lessons: (1) per-block __threadfence() in a gather kernel = L2 scrub storm
// (agg2 75->270 us, FETCH flat, BW 757 GB/s) — never fence-fold reductions;
// (2) agg1(+)gemm2 fusion neutral-to-negative (lgkmcnt-fenced LDS round trip
// serializes the node loop). Separate 2-us k_loss and separate k_gemm2 win.
__global__ __launch_bounds__(256) void k_gemm1_hist(
    const float* __restrict__ feat,
    const float* __restrict__ W1,
    const float* __restrict__ att_s,
    const float* __restrict__ att_d,
    float* __restrict__ h1, float* __restrict__ a_src, float* __restrict__ a_dst,
    const int* __restrict__ dst, int* __restrict__ btot, int* __restrict__ bh,
    int N, int E, int GH)
{
    __shared__ float Wh[32 * 64];   // gemm: [kk][c], 8 KB (hist reuses as int hist[1024])
    __shared__ float Fh[64 * 36];   // gemm: [r][kk], stride 36, 9.2 KB
    const int tid = threadIdx.x;

    if ((int)blockIdx.x < GH) {
        // -------- histogram branch: all per-edge atomics in LDS ---------------
        int* hist = (int*)Wh;
        for (int b = tid; b < BINS; b += 256) hist[b] = 0;
        __syncthreads();
        const int e0 = blockIdx.x * CHUNK;
        #pragma unroll
        for (int r = 0; r < 8; ++r) {
            int e = e0 + r * 1024 + tid * 4;
            if (e + 3 < E) {
                int4 d4 = *(const int4*)&dst[e];
                atomicAdd(&hist[d4.x >> BSH], 1);
                atomicAdd(&hist[d4.y >> BSH], 1);
                atomicAdd(&hist[d4.z >> BSH], 1);
                atomicAdd(&hist[d4.w >> BSH], 1);
            } else {
                for (int k = e; k < E && k < e + 4; ++k)
                    atomicAdd(&hist[dst[k] >> BSH], 1);
            }
        }
        __syncthreads();
        for (int b = tid; b < BINS; b += 256) {
            int c = hist[b];
            bh[(size_t)blockIdx.x * BINS + b] = c;      // coalesced 4 KB store
            if (c) atomicAdd(&btot[b * 16], c);         // no-return, padded line
        }
        return;
    }

    // -------- gemm1 branch: 64x64 tile, 4x4 register tile, K in 4 quarters ----
    const int tx = tid & 15, ty = tid >> 4;
    const int base = (blockIdx.x - GH) * 64;
    float4 acc0 = {0,0,0,0}, acc1 = {0,0,0,0}, acc2 = {0,0,0,0}, acc3 = {0,0,0,0};

    for (int p = 0; p < 4; ++p) {
        if (p) __syncthreads();
        for (int i = tid; i < 32 * 64; i += 256)
            Wh[i] = W1[p * 2048 + i];
        for (int i = tid; i < 64 * 32; i += 256) {
            int r = i >> 5, kk = i & 31;
            int n = base + r;
            Fh[r * 36 + kk] = (n < N) ? feat[(size_t)n * IN_F + p * 32 + kk] : 0.f;
        }
        __syncthreads();
        const float* wk = &Wh[4 * tx];
        const float* f0 = &Fh[(4 * ty + 0) * 36];
        const float* f1 = &Fh[(4 * ty + 1) * 36];
        const float* f2 = &Fh[(4 * ty + 2) * 36];
        const float* f3 = &Fh[(4 * ty + 3) * 36];
        #pragma unroll
        for (int kk = 0; kk < 32; kk += 4) {
            float4 fa = *(const float4*)&f0[kk];
            float4 fb = *(const float4*)&f1[kk];
            float4 fc = *(const float4*)&f2[kk];
            float4 fd = *(const float4*)&f3[kk];
            float4 w0 = *(const float4*)&wk[(kk + 0) * 64];
            float4 w1 = *(const float4*)&wk[(kk + 1) * 64];
            float4 w2 = *(const float4*)&wk[(kk + 2) * 64];
            float4 w3 = *(const float4*)&wk[(kk + 3) * 64];
            fma4(acc0, fa.x, w0); fma4(acc0, fa.y, w1); fma4(acc0, fa.z, w2); fma4(acc0, fa.w, w3);
            fma4(acc1, fb.x, w0); fma4(acc1, fb.y, w1); fma4(acc1, fb.z, w2); fma4(acc1, fb.w, w3);
            fma4(acc2, fc.x, w0); fma4(acc2, fc.y, w1); fma4(acc2, fc.z, w2); fma4(acc2, fc.w, w3);
            fma4(acc3, fd.x, w0); fma4(acc3, fd.y, w1); fma4(acc3, fd.z, w2); fma4(acc3, fd.w, w3);
        }
    }
    const float4 as4 = *(const float4*)&att_s[4 * tx];
    const float4 ad4 = *(const float4*)&att_d[4 * tx];
    float4 accs[4] = {acc0, acc1, acc2, acc3};
    #pragma unroll
    for (int i = 0; i < 4; ++i) {
        int n = base + 4 * ty + i;
        if (n < N) {
            *(float4*)&h1[(size_t)n * D1 + 4 * tx] = accs[i];
            float ps = accs[i].x * as4.x + accs[i].y * as4.y + accs[i].z * as4.z + accs[i].w * as4.w;
            float pd = accs[i].x * ad4.x + accs[i].y * ad4.y + accs[i].z * ad4.z + accs[i].w * ad4.w;
            ps += __shfl_xor(ps, 1);
            pd += __shfl_xor(pd, 1);
            if ((tx & 1) == 0) {
                a_src[n * NHEAD + (tx >> 1)] = ps;
                a_dst[n * NHEAD + (tx >> 1)] = pd;
            }
        }
    }
}

__device__ __forceinline__ int block_incl_scan(int v, int tid, int* lds4)
{
    int lane = tid & 63, w = tid >> 6;
    #pragma unroll
    for (int off = 1; off < 64; off <<= 1) {
        int t = __shfl_up(v, off);
        if (lane >= off) v += t;
    }
    if (lane == 63) lds4[w] = v;
    __syncthreads();
    int add = 0;
    #pragma unroll
    for (int i = 0; i < 4; ++i)
        if (i < w) add += lds4[i];
    __syncthreads();
    return v + add;
}

// Scan the 1024 bucket totals -> bucket bases; init the padded global cursors;
// zero the loss bins (folded here).
__global__ __launch_bounds__(256) void k_bscan(
    const int* __restrict__ btot, int* __restrict__ bbase, int* __restrict__ gcur,
    double* __restrict__ bins)
{
    __shared__ int lds4[4];
    const int tid = threadIdx.x;
    bins[tid] = 0.0;
    int c0 = btot[(4 * tid + 0) * 16];
    int c1 = btot[(4 * tid + 1) * 16];
    int c2 = btot[(4 * tid + 2) * 16];
    int c3 = btot[(4 * tid + 3) * 16];
    int v = c0 + c1 + c2 + c3;
    int incl = block_incl_scan(v, tid, lds4);
    int b0 = incl - v, b1 = b0 + c0, b2 = b1 + c1, b3 = b2 + c2;
    bbase[4 * tid + 0] = b0; gcur[(4 * tid + 0) * 16] = b0;
    bbase[4 * tid + 1] = b1; gcur[(4 * tid + 1) * 16] = b1;
    bbase[4 * tid + 2] = b2; gcur[(4 * tid + 2) * 16] = b2;
    bbase[4 * tid + 3] = b3; gcur[(4 * tid + 3) * 16] = b3;
}

// Scatter edges into their dst-bucket. Packed entry: (dst&127)<<17 | src.
__global__ __launch_bounds__(256) void k_scatter(
    const int* __restrict__ src, const int* __restrict__ dst,
    const int* __restrict__ bh, int* __restrict__ gcur,
    int* __restrict__ bucketed, int E)
{
    __shared__ int base[BINS], cur[BINS];
    const int tid = threadIdx.x;
    for (int b = tid; b < BINS; b += 256) {
        cur[b] = 0;
        int c = bh[(size_t)blockIdx.x * BINS + b];
        if (c) base[b] = atomicAdd(&gcur[b * 16], c);
    }
    __syncthreads();
    const int e0 = blockIdx.x * CHUNK;
    #pragma unroll
    for (int r = 0; r < 8; ++r) {
        int e = e0 + r * 1024 + tid * 4;
        if (e + 3 < E) {
            int4 d4 = *(const int4*)&dst[e];
            int4 s4 = *(const int4*)&src[e];
            int bx, rx;
            bx = d4.x >> BSH; rx = atomicAdd(&cur[bx], 1); bucketed[base[bx] + rx] = ((d4.x & 127) << 17) | s4.x;
            bx = d4.y >> BSH; rx = atomicAdd(&cur[bx], 1); bucketed[base[bx] + rx] = ((d4.y & 127) << 17) | s4.y;
            bx = d4.z >> BSH; rx = atomicAdd(&cur[bx], 1); bucketed[base[bx] + rx] = ((d4.z & 127) << 17) | s4.z;
            bx = d4.w >> BSH; rx = atomicAdd(&cur[bx], 1); bucketed[base[bx] + rx] = ((d4.w & 127) << 17) | s4.w;
        } else {
            for (int k = e; k < E && k < e + 4; ++k) {
                int d = dst[k];
                int bx = d >> BSH;
                int rx = atomicAdd(&cur[bx], 1);
                bucketed[base[bx] + rx] = ((d & 127) << 17) | src[k];
            }
        }
    }
}

// One block per bucket: count 128 local nodes in LDS, scan in LDS, emit
// deg/rowstart directly, then scatter the bucket into final CSR positions.
__global__ __launch_bounds__(256) void k_seg(
    const int* __restrict__ btot, const int* __restrict__ bbase,
    const int* __restrict__ bucketed,
    int* __restrict__ deg, int* __restrict__ rowstart, int* __restrict__ srcs, int N)
{
    __shared__ int cnt[128], cur[128], lb[128];
    const int tid = threadIdx.x;
    const int b = blockIdx.x;
    const int gs = bbase[b];
    const int sz = btot[b * 16];
    if (tid < 128) { cnt[tid] = 0; cur[tid] = 0; }
    __syncthreads();
    for (int i = tid; i < sz; i += 256)
        atomicAdd(&cnt[bucketed[gs + i] >> 17], 1);
    __syncthreads();
    if (tid < 128) lb[tid] = cnt[tid];
    __syncthreads();
    #pragma unroll
    for (int off = 1; off < 128; off <<= 1) {
        int t = 0;
        if (tid < 128 && tid >= off) t = lb[tid - off];
        __syncthreads();
        if (tid < 128 && tid >= off) lb[tid] += t;
        __syncthreads();
    }
    if (tid < 128) {
        int ex = lb[tid] - cnt[tid];   // exclusive local base
        lb[tid] = ex;
        int d = b * 128 + tid;
        if (d < N) { deg[d] = cnt[tid]; rowstart[d] = gs + ex; }
    }
    __syncthreads();
    for (int i = tid; i < sz; i += 256) {
        int v = bucketed[gs + i];
        int d7 = v >> 17;
        int r = atomicAdd(&cur[d7], 1);
        srcs[gs + lb[d7] + r] = v & 0x1FFFF;
    }
}

// ---------------- Layer-1 aggregation ------------------------------------------
// De-LDS'd: lane (t=j&15, q=j>>4) loads its q-group's 4 srcs directly, loads
// a_s itself, exp in-register. No LDS, no fences. Memory wall quadruple-
// confirmed: FETCH pinned 267 MB @ ~3.7 TB/s across 4 structures.
__global__ __launch_bounds__(256) void k_agg1(
    const int* __restrict__ deg, const int* __restrict__ rowstart,
    const int* __restrict__ srcs,
    const float* __restrict__ a_s, const float* __restrict__ a_d,
    const float* __restrict__ h1, const float* __restrict__ b1,
    float* __restrict__ x, int N)
{
    const int tid = threadIdx.x, w = tid >> 6, j = tid & 63;
    const int t = j & 15, q = j >> 4;
    const int n = blockIdx.x * 4 + w;
    if (n >= N) return;
    const int rlen = deg[n];
    const int row = rowstart[n];
    const int h = t >> 1;
    const float ad = a_d[n * NHEAD + h];
    float4 acc = {0.f, 0.f, 0.f, 0.f};
    float den = 0.f;
    for (int base = 0; base < rlen; base += 16) {
        int mTot = rlen - base;
        if (4 * q < mTot) {
            int rem = mTot - 4 * q;
            int i0 = row + base + 4 * q;
            int s0 = srcs[i0];
            int s1 = rem > 1 ? srcs[i0 + 1] : 0;
            int s2 = rem > 2 ? srcs[i0 + 2] : 0;
            int s3 = rem > 3 ? srcs[i0 + 3] : 0;
            float v0 = a_s[s0 * NHEAD + h] + ad;
            float v1 = a_s[s1 * NHEAD + h] + ad;
            float v2 = a_s[s2 * NHEAD + h] + ad;
            float v3 = a_s[s3 * NHEAD + h] + ad;
            v0 = v0 > 0.f ? v0 : NEG * v0;
            v1 = v1 > 0.f ? v1 : NEG * v1;
            v2 = v2 > 0.f ? v2 : NEG * v2;
            v3 = v3 > 0.f ? v3 : NEG * v3;
            float e0 = __expf(v0);
            float e1 = rem > 1 ? __expf(v1) : 0.f;
            float e2 = rem > 2 ? __expf(v2) : 0.f;
            float e3 = rem > 3 ? __expf(v3) : 0.f;
            float4 l0 = *(const float4*)&h1[(size_t)s0 * D1 + 4 * t];
            float4 l1 = *(const float4*)&h1[(size_t)s1 * D1 + 4 * t];
            float4 l2 = *(const float4*)&h1[(size_t)s2 * D1 + 4 * t];
            float4 l3 = *(const float4*)&h1[(size_t)s3 * D1 + 4 * t];
            fma4(acc, e0, l0); fma4(acc, e1, l1);
            fma4(acc, e2, l2); fma4(acc, e3, l3);
            den += (e0 + e1) + (e2 + e3);
        }
    }
    // merge the 4 q-replicas (den rides along)
    acc.x += __shfl_xor(acc.x, 16); acc.y += __shfl_xor(acc.y, 16);
    acc.z += __shfl_xor(acc.z, 16); acc.w += __shfl_xor(acc.w, 16);
    den   += __shfl_xor(den, 16);
    acc.x += __shfl_xor(acc.x, 32); acc.y += __shfl_xor(acc.y, 32);
    acc.z += __shfl_xor(acc.z, 32); acc.w += __shfl_xor(acc.w, 32);
    den   += __shfl_xor(den, 32);
    if (q == 0) {
        float4 b = *(const float4*)&b1[4 * t];
        float4 o;
        o.x = acc.x / den + b.x; o.y = acc.y / den + b.y;
        o.z = acc.z / den + b.z; o.w = acc.w / den + b.w;
        o.x = o.x > 0.f ? o.x : expm1f(o.x);
        o.y = o.y > 0.f ? o.y : expm1f(o.y);
        o.z = o.z > 0.f ? o.z : expm1f(o.z);
        o.w = o.w > 0.f ? o.w : expm1f(o.w);
        *(float4*)&x[(size_t)n * D1 + 4 * t] = o;
    }
}

// ---------------- Kernel D: h2 = x @ W2, a_src2/a_dst2 (4x4 register tile) ----------------
__global__ __launch_bounds__(256) void k_gemm2(
    const float* __restrict__ x,
    const float* __restrict__ W2,
    const float* __restrict__ att_s,
    const float* __restrict__ att_d,
    float* __restrict__ h2, float* __restrict__ a_src, float* __restrict__ a_dst,
    int N)
{
    __shared__ float Wh[64 * 64];
    __shared__ float Fh[64 * 68];
    const int tid = threadIdx.x;
    const int tx = tid & 15, ty = tid >> 4;
    const int base = blockIdx.x * 64;
    for (int i = tid; i < 64 * 64; i += 256)
        Wh[i] = W2[i];
    for (int i = tid; i < 64 * 64; i += 256) {
        int r = i >> 6, kk = i & 63;
        int n = base + r;
        Fh[r * 68 + kk] = (n < N) ? x[(size_t)n * 64 + kk] : 0.f;
    }
    __syncthreads();
    float4 acc0 = {0,0,0,0}, acc1 = {0,0,0,0}, acc2 = {0,0,0,0}, acc3 = {0,0,0,0};
    const float* wk = &Wh[4 * tx];
    const float* f0 = &Fh[(4 * ty + 0) * 68];
    const float* f1 = &Fh[(4 * ty + 1) * 68];
    const float* f2 = &Fh[(4 * ty + 2) * 68];
    const float* f3 = &Fh[(4 * ty + 3) * 68];
    #pragma unroll 4
    for (int kk = 0; kk < 64; kk += 4) {
        float4 fa = *(const float4*)&f0[kk];
        float4 fb = *(const float4*)&f1[kk];
        float4 fc = *(const float4*)&f2[kk];
        float4 fd = *(const float4*)&f3[kk];
        float4 w0 = *(const float4*)&wk[(kk + 0) * 64];
        float4 w1 = *(const float4*)&wk[(kk + 1) * 64];
        float4 w2 = *(const float4*)&wk[(kk + 2) * 64];
        float4 w3 = *(const float4*)&wk[(kk + 3) * 64];
        fma4(acc0, fa.x, w0); fma4(acc0, fa.y, w1); fma4(acc0, fa.z, w2); fma4(acc0, fa.w, w3);
        fma4(acc1, fb.x, w0); fma4(acc1, fb.y, w1); fma4(acc1, fb.z, w2); fma4(acc1, fb.w, w3);
        fma4(acc2, fc.x, w0); fma4(acc2, fc.y, w1); fma4(acc2, fc.z, w2); fma4(acc2, fc.w, w3);
        fma4(acc3, fd.x, w0); fma4(acc3, fd.y, w1); fma4(acc3, fd.z, w2); fma4(acc3, fd.w, w3);
    }
    const float4 as4 = *(const float4*)&att_s[4 * tx];
    const float4 ad4 = *(const float4*)&att_d[4 * tx];
    float4 accs[4] = {acc0, acc1, acc2, acc3};
    #pragma unroll
    for (int i = 0; i < 4; ++i) {
        int n = base + 4 * ty + i;
        if (n < N) {
            *(float4*)&h2[(size_t)n * 64 + 4 * tx] = accs[i];
            float ps = accs[i].x * as4.x + accs[i].y * as4.y + accs[i].z * as4.z + accs[i].w * as4.w;
            float pd = accs[i].x * ad4.x + accs[i].y * ad4.y + accs[i].z * ad4.z + accs[i].w * ad4.w;
            ps += __shfl_xor(ps, 1); pd += __shfl_xor(pd, 1);
            ps += __shfl_xor(ps, 2); pd += __shfl_xor(pd, 2);
            ps += __shfl_xor(ps, 4); pd += __shfl_xor(pd, 4);
            ps += __shfl_xor(ps, 8); pd += __shfl_xor(pd, 8);
            if (tx == 0) { a_src[n] = ps; a_dst[n] = pd; }
        }
    }
}

// ---------------- Layer-2 aggregation + bias + log-softmax + argmax + NLL ------
// Register-source __shfl broadcasts (no LDS staging, no fences).
__global__ __launch_bounds__(256) void k_agg2(
    const int* __restrict__ deg, const int* __restrict__ rowstart,
    const int* __restrict__ srcs,
    const float* __restrict__ a_s, const float* __restrict__ a_d,
    const float* __restrict__ h2, const float* __restrict__ b2,
    const int* __restrict__ label,
    float* __restrict__ dout, double* __restrict__ bins, int N)
{
    __shared__ float snll[16];
    const int tid = threadIdx.x, j = tid & 63;
    const int t = j & 15, g16 = j & 0x30;  // node's 16-lane group base within wave
    const int n = blockIdx.x * 16 + (tid >> 4);
    if (tid < 16) snll[tid] = 0.f;
    __syncthreads();
    const bool valid = (n < N);
    const int rlen = valid ? deg[n] : 0;
    const int row  = valid ? rowstart[n] : 0;
    const float ad = valid ? a_d[n] : 0.f;
    float4 acc = {0.f, 0.f, 0.f, 0.f};
    float den = 0.f;
    for (int base = 0; base < rlen; base += 16) {
        int m = rlen - base; if (m > 16) m = 16;
        int myS = 0; float ex = 0.f;
        if (t < m) {
            myS = srcs[row + base + t];
            float v = a_s[myS] + ad;
            v = v > 0.f ? v : NEG * v;
            ex = __expf(v);
        }
        float ds = ex;
        ds += __shfl_xor(ds, 1); ds += __shfl_xor(ds, 2);
        ds += __shfl_xor(ds, 4); ds += __shfl_xor(ds, 8);
        den += ds;
        for (int kb = 0; kb < m; kb += 4) {            // kb in {0,4,8,12}
            int s0 = __shfl(myS, g16 | (kb + 0));
            int s1 = __shfl(myS, g16 | (kb + 1));
            int s2 = __shfl(myS, g16 | (kb + 2));
            int s3 = __shfl(myS, g16 | (kb + 3));
            float e0 = __shfl(ex, g16 | (kb + 0));
            float e1 = __shfl(ex, g16 | (kb + 1));
            float e2 = __shfl(ex, g16 | (kb + 2));
            float e3 = __shfl(ex, g16 | (kb + 3));
            float4 l0 = *(const float4*)&h2[(size_t)s0 * 64 + 4 * t];
            float4 l1 = *(const float4*)&h2[(size_t)s1 * 64 + 4 * t];
            float4 l2 = *(const float4*)&h2[(size_t)s2 * 64 + 4 * t];
            float4 l3 = *(const float4*)&h2[(size_t)s3 * 64 + 4 * t];
            fma4(acc, e0, l0);
            fma4(acc, e1, l1);
            fma4(acc, e2, l2);
            fma4(acc, e3, l3);
        }
    }
    float4 b = *(const float4*)&b2[4 * t];
    float4 sc;
    sc.x = acc.x / den + b.x; sc.y = acc.y / den + b.y;
    sc.z = acc.z / den + b.z; sc.w = acc.w / den + b.w;
    float mv = sc.x; int mi = 4 * t;
    if (sc.y > mv) { mv = sc.y; mi = 4 * t + 1; }
    if (sc.z > mv) { mv = sc.z; mi = 4 * t + 2; }
    if (sc.w > mv) { mv = sc.w; mi = 4 * t + 3; }
    #pragma unroll
    for (int off = 1; off < 16; off <<= 1) {
        float ov = __shfl_xor(mv, off);
        int oi = __shfl_xor(mi, off);
        if (ov > mv || (ov == mv && oi < mi)) { mv = ov; mi = oi; }
    }
    float se = __expf(sc.x - mv) + __expf(sc.y - mv) + __expf(sc.z - mv) + __expf(sc.w - mv);
    #pragma unroll
    for (int off = 1; off < 16; off <<= 1) se += __shfl_xor(se, off);
    int lab = valid ? label[n] : 0;
    int comp = lab & 3;
    float cl = comp == 0 ? sc.x : comp == 1 ? sc.y : comp == 2 ? sc.z : sc.w;
    float sl = __shfl(cl, g16 | (lab >> 2));
    if (t == 0 && valid) {
        snll[tid >> 4] = mv + logf(se) - sl;
        dout[1 + n] = (float)mi;
        dout[1 + (size_t)N + n] = (float)lab;
    }
    __syncthreads();
    if (tid == 0) {
        double bs = 0.0;
        #pragma unroll
        for (int i = 0; i < 16; ++i) bs += (double)snll[i];
        atomicAdd(&bins[blockIdx.x & (NBINS - 1)], bs);
    }
}

// Single block of 256: reduce NBINS doubles -> loss
__global__ __launch_bounds__(256) void k_loss(
    const double* __restrict__ bins, float* __restrict__ dout, int N)
{
    __shared__ double sw[4];
    const int tid = threadIdx.x;
    double v = bins[tid];
    #pragma unroll
    for (int off = 1; off < 64; off <<= 1) v += __shfl_xor(v, off);
    if ((tid & 63) == 0) sw[tid >> 6] = v;
    __syncthreads();
    if (tid == 0)
        dout[0] = (float)((sw[0] + sw[1] + sw[2] + sw[3]) / (double)N);
}

extern "C" void kernel_launch(void* const* d_in, const int* in_sizes, int n_in,
                              void* d_out, int out_size, void* d_ws, size_t ws_size,
                              hipStream_t stream)
{
    const float* feat   = (const float*)d_in[1];
    const int*   edge   = (const int*)d_in[2];
    const int*   label  = (const int*)d_in[4];
    const float* W1     = (const float*)d_in[5];
    const float* att_s1 = (const float*)d_in[6];
    const float* att_d1 = (const float*)d_in[7];
    const float* b1     = (const float*)d_in[8];
    const float* W2     = (const float*)d_in[9];
    const float* att_s2 = (const float*)d_in[10];
    const float* att_d2 = (const float*)d_in[11];
    const float* b2     = (const float*)d_in[12];

    const int N = in_sizes[0];
    const int E = in_sizes[2] / 2;
    const int* src = edge;
    const int* dst = edge + E;

    // workspace layout:
    float* bufA = (float*)d_ws;               // N*64: h1 / h2 (no aliases)
    float* bufB = bufA + (size_t)N * 64;      // N*64: x; aliases CSR-build scratch
    float* a_s1 = bufB + (size_t)N * 64;      // N*8 (layer2: a_s2=[0..N), a_d2=[N..2N))
    float* a_d1 = a_s1 + (size_t)N * 8;       // N*8
    int*   deg  = (int*)(a_d1 + (size_t)N * 8); // N
    int*   rowstart = deg + N;                // N (absolute CSR row starts)
    int*   srcs = rowstart + N;               // E
    double* bins = (double*)(((uintptr_t)(srcs + E) + 7) & ~(uintptr_t)7);

    // Aliases in bufB — all dead before k_agg1 writes x:
    int* bucketed = (int*)bufB;               // E   packed (dst&127)<<17 | src
    int* btot  = bucketed + E;                // BINS*16 (padded: 1 counter / 64B line)
    int* gcur  = btot + BINS * 16;            // BINS*16 (padded cursors)
    int* bbase = gcur + BINS * 16;            // BINS
    int* bh    = bbase + BINS;                // GH*BINS per-block histograms

    float* a_s2 = a_s1;
    float* a_d2 = a_s1 + N;

    float* out = (float*)d_out;

    const int GH    = (E + CHUNK - 1) / CHUNK;
    const int G1    = (N + 63) / 64;
    const int NBUCK = (N + 127) / 128;

    hipMemsetAsync(btot, 0, (size_t)BINS * 16 * sizeof(int), stream);

    // bucket-hist (LDS atomics) overlapped with gemm1; then bucket scan; then
    // scatter into buckets; then per-bucket sort -> deg/rowstart/srcs.
    k_gemm1_hist<<<GH + G1, 256, 0, stream>>>(feat, W1, att_s1, att_d1,
                                              bufA, a_s1, a_d1,
                                              dst, btot, bh, N, E, GH);
    k_bscan  <<<1, 256, 0, stream>>>(btot, bbase, gcur, bins);
    k_scatter<<<GH, 256, 0, stream>>>(src, dst, bh, gcur, bucketed, E);
    k_seg    <<<NBUCK, 256, 0, stream>>>(btot, bbase, bucketed, deg, rowstart, srcs, N);

    k_agg1 <<<(N + 3) / 4, 256, 0, stream>>>(deg, rowstart, srcs, a_s1, a_d1,
                                             bufA, b1, bufB, N);
    k_gemm2<<<G1, 256, 0, stream>>>(bufB, W2, att_s2, att_d2, bufA, a_s2, a_d2, N);
    k_agg2 <<<(N + 15) / 16, 256, 0, stream>>>(deg, rowstart, srcs, a_s2, a_d2,
                                               bufA, b2, label, out, bins, N);
    k_loss <<<1, 256, 0, stream>>>(bins, out, N);
}